// Round 8
// baseline (185.104 us; speedup 1.0000x reference)
//
#include <hip/hip_runtime.h>
#include <hip/hip_bf16.h>

// B=4, T=2048, C=1024, D=64 ; causal single-head attention, fp32 in/out.
constexpr int Bn = 4;
constexpr int Tn = 2048;
constexpr int Cn = 1024;
constexpr int Dn = 64;

typedef __attribute__((ext_vector_type(8))) short short8;  // 8 bf16 (4 VGPRs)
typedef __attribute__((ext_vector_type(4))) float f32x4;   // MFMA acc

// fp32 -> bf16 bits, round-to-nearest-even
__device__ inline short f2bf(float f) {
    unsigned u = __builtin_bit_cast(unsigned, f);
    u += 0x7FFFu + ((u >> 16) & 1u);
    return (short)(u >> 16);
}

// ---------------------------------------------------------------------------
// Kernel 0: weights -> bf16, transposed: wt[sel][n=0..63][k=0..1023]
// ---------------------------------------------------------------------------
__global__ __launch_bounds__(256) void prep_w(
    const float* __restrict__ wq, const float* __restrict__ wk,
    const float* __restrict__ wv, short* __restrict__ wt)
{
    const int sel = blockIdx.x >> 4;           // 48 blocks: 3 sel x 16 parts
    const float* w = sel == 0 ? wq : (sel == 1 ? wk : wv);
    short* o = wt + (size_t)sel * Dn * Cn;
    const int base = (blockIdx.x & 15) * 4096; // 65536/16
    for (int idx = base + threadIdx.x; idx < base + 4096; idx += 256) {
        int n = idx >> 10, k = idx & 1023;     // write o[n][k] coalesced
        o[idx] = f2bf(w[k * Dn + n]);
    }
}

// ---------------------------------------------------------------------------
// Kernel 1: QKV projection via bf16 MFMA.  One wave per block, 16 rows each.
// A-frag = x rows (fp32->bf16 on the fly), B-frags = wt (n-major).
// Outputs: Qbf (b,t,d) pre-scaled by 0.125, Kbf (b,t,d), Vt (b,d,t).
// Fragment convention (consistent A/B => k-permutation cancels):
//   A slot(lane,j) = A[lane&15][8*(lane>>4)+j], B slot = B[8*(lane>>4)+j][lane&15]
//   C/D (verified, m89): row=(lane>>4)*4+reg, col=lane&15
// ---------------------------------------------------------------------------
__global__ __launch_bounds__(64) void qkv_mfma(
    const float* __restrict__ x, const short* __restrict__ wt,
    const float* __restrict__ bq, const float* __restrict__ bk,
    const float* __restrict__ bv,
    short* __restrict__ Qbf, short* __restrict__ Kbf, short* __restrict__ Vt)
{
    const int l = threadIdx.x;
    const int i = l & 15, g = l >> 4;
    const int rowbase = blockIdx.x * 16;

    f32x4 aq[4], ak[4], av[4];
    #pragma unroll
    for (int nt = 0; nt < 4; ++nt) {
        #pragma unroll
        for (int r = 0; r < 4; ++r) { aq[nt][r] = 0.f; ak[nt][r] = 0.f; av[nt][r] = 0.f; }
    }

    const float* xrow = x + (size_t)(rowbase + i) * Cn;   // A row = lane&15

    for (int k0 = 0; k0 < Cn; k0 += 32) {
        float4 x0 = *reinterpret_cast<const float4*>(xrow + k0 + 8 * g);
        float4 x1 = *reinterpret_cast<const float4*>(xrow + k0 + 8 * g + 4);
        short8 af;
        af[0] = f2bf(x0.x); af[1] = f2bf(x0.y); af[2] = f2bf(x0.z); af[3] = f2bf(x0.w);
        af[4] = f2bf(x1.x); af[5] = f2bf(x1.y); af[6] = f2bf(x1.z); af[7] = f2bf(x1.w);
        #pragma unroll
        for (int nt = 0; nt < 4; ++nt) {
            const short* wb = wt + (size_t)(nt * 16 + i) * Cn + k0 + 8 * g;
            short8 bfq = *reinterpret_cast<const short8*>(wb);
            short8 bfk = *reinterpret_cast<const short8*>(wb + Dn * Cn);
            short8 bfv = *reinterpret_cast<const short8*>(wb + 2 * Dn * Cn);
            aq[nt] = __builtin_amdgcn_mfma_f32_16x16x32_bf16(af, bfq, aq[nt], 0, 0, 0);
            ak[nt] = __builtin_amdgcn_mfma_f32_16x16x32_bf16(af, bfk, ak[nt], 0, 0, 0);
            av[nt] = __builtin_amdgcn_mfma_f32_16x16x32_bf16(af, bfv, av[nt], 0, 0, 0);
        }
    }

    #pragma unroll
    for (int r = 0; r < 4; ++r) {
        const int rho = rowbase + 4 * g + r;          // C/D row
        const int b = rho >> 11, t = rho & (Tn - 1);
        #pragma unroll
        for (int nt = 0; nt < 4; ++nt) {
            const int n = nt * 16 + i;                // C/D col
            Qbf[(size_t)rho * Dn + n] = f2bf((aq[nt][r] + bq[n]) * 0.125f);
            Kbf[(size_t)rho * Dn + n] = f2bf(ak[nt][r] + bk[n]);
            Vt[((size_t)b * Dn + n) * Tn + t] = f2bf(av[nt][r] + bv[n]);
        }
    }
}

// ---------------------------------------------------------------------------
// Kernel 2: fused causal flash attention.  Grid (T/16, B), ONE wave per block
// owning 16 q-rows (no block barriers anywhere).  KV chunk = 64 keys, read
// straight from global (L2-resident: K+V = 512 KB/batch).  P relayout via a
// private LDS tile [16][72] (pad 72 -> conflict-floor; 16B-aligned).
// ---------------------------------------------------------------------------
__global__ __launch_bounds__(64) void attn_fused(
    const short* __restrict__ Qbf, const short* __restrict__ Kbf,
    const short* __restrict__ Vt, float* __restrict__ out)
{
    __shared__ __align__(16) short Plds[16][72];

    const int l = threadIdx.x;
    const int i = l & 15, g = l >> 4;
    const int b = blockIdx.y;
    const int qw = blockIdx.x * 16;                   // wave's first q-row

    const short* Qb = Qbf + (size_t)b * Tn * Dn;
    const short* Kb = Kbf + (size_t)b * Tn * Dn;
    const short* Vb = Vt + (size_t)b * Dn * Tn;

    // Q fragments for this wave's 16 rows (A row = lane&15), held in regs
    short8 qf0 = *reinterpret_cast<const short8*>(Qb + (size_t)(qw + i) * Dn + 8 * g);
    short8 qf1 = *reinterpret_cast<const short8*>(Qb + (size_t)(qw + i) * Dn + 32 + 8 * g);

    f32x4 o4[4];
    f32x4 m, lsum;
    #pragma unroll
    for (int r = 0; r < 4; ++r) { m[r] = -1e30f; lsum[r] = 0.f; }
    #pragma unroll
    for (int dt = 0; dt < 4; ++dt)
        #pragma unroll
        for (int r = 0; r < 4; ++r) o4[dt][r] = 0.f;

    const int nch = (qw + 79) >> 6;                   // chunks covering keys <= qw+15
    for (int kb = 0; kb < nch; ++kb) {
        const int K0 = kb * 64;

        // ---- S = Q K^T (rows=q, cols=key), 2 d-chunks x 4 key-tiles ----
        f32x4 s[4];
        #pragma unroll
        for (int nt = 0; nt < 4; ++nt)
            #pragma unroll
            for (int r = 0; r < 4; ++r) s[nt][r] = 0.f;
        #pragma unroll
        for (int nt = 0; nt < 4; ++nt) {
            const short* kr = Kb + (size_t)(K0 + nt * 16 + i) * Dn + 8 * g;
            short8 kf0 = *reinterpret_cast<const short8*>(kr);
            short8 kf1 = *reinterpret_cast<const short8*>(kr + 32);
            s[nt] = __builtin_amdgcn_mfma_f32_16x16x32_bf16(qf0, kf0, s[nt], 0, 0, 0);
            s[nt] = __builtin_amdgcn_mfma_f32_16x16x32_bf16(qf1, kf1, s[nt], 0, 0, 0);
        }

        // ---- causal mask (only near the diagonal) ----
        if (K0 + 63 > qw) {
            #pragma unroll
            for (int nt = 0; nt < 4; ++nt)
                #pragma unroll
                for (int r = 0; r < 4; ++r) {
                    if (K0 + nt * 16 + i > qw + 4 * g + r) s[nt][r] = -1e30f;
                }
        }

        // ---- online softmax: row stats over the 16 key-lanes ----
        f32x4 rm;
        #pragma unroll
        for (int r = 0; r < 4; ++r)
            rm[r] = fmaxf(fmaxf(s[0][r], s[1][r]), fmaxf(s[2][r], s[3][r]));
        #pragma unroll
        for (int msk = 1; msk < 16; msk <<= 1)
            #pragma unroll
            for (int r = 0; r < 4; ++r) rm[r] = fmaxf(rm[r], __shfl_xor(rm[r], msk));

        f32x4 scl;
        #pragma unroll
        for (int r = 0; r < 4; ++r) {
            float mn = fmaxf(m[r], rm[r]);
            scl[r] = __expf(m[r] - mn);
            m[r] = mn;
            lsum[r] *= scl[r];
        }
        #pragma unroll
        for (int dt = 0; dt < 4; ++dt)
            #pragma unroll
            for (int r = 0; r < 4; ++r) o4[dt][r] *= scl[r];

        // ---- P = exp(S-m): accumulate row sums, spill bf16 to LDS ----
        f32x4 rs;
        #pragma unroll
        for (int r = 0; r < 4; ++r) rs[r] = 0.f;
        #pragma unroll
        for (int nt = 0; nt < 4; ++nt)
            #pragma unroll
            for (int r = 0; r < 4; ++r) {
                float p = __expf(s[nt][r] - m[r]);
                rs[r] += p;
                Plds[4 * g + r][nt * 16 + i] = f2bf(p);   // true (row,key) coords
            }
        #pragma unroll
        for (int msk = 1; msk < 16; msk <<= 1)
            #pragma unroll
            for (int r = 0; r < 4; ++r) rs[r] += __shfl_xor(rs[r], msk);
        #pragma unroll
        for (int r = 0; r < 4; ++r) lsum[r] += rs[r];

        // single-wave LDS roundtrip: drain writes, block compiler reordering
        asm volatile("s_waitcnt lgkmcnt(0)" ::: "memory");
        __builtin_amdgcn_sched_barrier(0);

        // ---- O += P V : A-frags from Plds, B-frags from Vt (L2) ----
        short8 pf0 = *reinterpret_cast<const short8*>(&Plds[i][8 * g]);
        short8 pf1 = *reinterpret_cast<const short8*>(&Plds[i][32 + 8 * g]);
        #pragma unroll
        for (int dt = 0; dt < 4; ++dt) {
            const short* vr = Vb + (size_t)(dt * 16 + i) * Tn + K0 + 8 * g;
            short8 vf0 = *reinterpret_cast<const short8*>(vr);
            short8 vf1 = *reinterpret_cast<const short8*>(vr + 32);
            o4[dt] = __builtin_amdgcn_mfma_f32_16x16x32_bf16(pf0, vf0, o4[dt], 0, 0, 0);
            o4[dt] = __builtin_amdgcn_mfma_f32_16x16x32_bf16(pf1, vf1, o4[dt], 0, 0, 0);
        }
    }

    // ---- epilogue: normalize, fp32 store ----
    #pragma unroll
    for (int r = 0; r < 4; ++r) {
        const float inv = 1.0f / lsum[r];
        const int trow = qw + 4 * g + r;
        #pragma unroll
        for (int dt = 0; dt < 4; ++dt)
            out[((size_t)b * Tn + trow) * Dn + dt * 16 + i] = o4[dt][r] * inv;
    }
}

// ---------------------------------------------------------------------------
extern "C" void kernel_launch(void* const* d_in, const int* in_sizes, int n_in,
                              void* d_out, int out_size, void* d_ws, size_t ws_size,
                              hipStream_t stream) {
    const float* x  = (const float*)d_in[0];
    const float* wq = (const float*)d_in[1];
    const float* wk = (const float*)d_in[2];
    const float* wv = (const float*)d_in[3];
    const float* bq = (const float*)d_in[4];
    const float* bk = (const float*)d_in[5];
    const float* bv = (const float*)d_in[6];
    float* out = (float*)d_out;

    short* wt  = (short*)d_ws;                       // 3*64*1024  bf16
    short* Qbf = wt + 3 * Dn * Cn;                   // 4*2048*64  bf16 each
    short* Kbf = Qbf + (size_t)Bn * Tn * Dn;
    short* Vt  = Kbf + (size_t)Bn * Tn * Dn;         // transposed (b,d,t)

    prep_w<<<48, 256, 0, stream>>>(wq, wk, wv, wt);
    qkv_mfma<<<(Bn * Tn) / 16, 64, 0, stream>>>(x, wt, bq, bk, bv, Qbf, Kbf, Vt);
    attn_fused<<<dim3(Tn / 16, Bn), 64, 0, stream>>>(Qbf, Kbf, Vt, out);
}

// Round 9
// 149.464 us; speedup vs baseline: 1.2384x; 1.2384x over previous
//
#include <hip/hip_runtime.h>
#include <hip/hip_bf16.h>

// B=4, T=2048, C=1024, D=64 ; causal single-head attention, fp32 in/out.
constexpr int Bn = 4;
constexpr int Tn = 2048;
constexpr int Cn = 1024;
constexpr int Dn = 64;

typedef __attribute__((ext_vector_type(8))) short short8;  // 8 bf16 (4 VGPRs)
typedef __attribute__((ext_vector_type(4))) float f32x4;   // MFMA acc

// fp32 -> bf16 bits, round-to-nearest-even
__device__ inline short f2bf(float f) {
    unsigned u = __builtin_bit_cast(unsigned, f);
    u += 0x7FFFu + ((u >> 16) & 1u);
    return (short)(u >> 16);
}

// ---------------------------------------------------------------------------
// Kernel 0: weights -> bf16, transposed: wt[sel][n=0..63][k=0..1023]
// ---------------------------------------------------------------------------
__global__ __launch_bounds__(256) void prep_w(
    const float* __restrict__ wq, const float* __restrict__ wk,
    const float* __restrict__ wv, short* __restrict__ wt)
{
    const int sel = blockIdx.x >> 4;           // 48 blocks: 3 sel x 16 parts
    const float* w = sel == 0 ? wq : (sel == 1 ? wk : wv);
    short* o = wt + (size_t)sel * Dn * Cn;
    const int base = (blockIdx.x & 15) * 4096; // 65536/16
    for (int idx = base + threadIdx.x; idx < base + 4096; idx += 256) {
        int n = idx >> 10, k = idx & 1023;     // write o[n][k] coalesced
        o[idx] = f2bf(w[k * Dn + n]);
    }
}

// ---------------------------------------------------------------------------
// Kernel 1: QKV projection via bf16 MFMA.  Grid (512, 3): blockIdx.y = sel,
// one wave per block computing 16 rows x 64 cols of ONE output matrix.
// (Round-8 profile: 512 waves total was latency-bound at 2.7% occupancy;
//  sel-split triples wave count and cuts the per-iter MFMA chain 12->4.)
// Fragment convention (consistent A/B => k-permutation cancels):
//   A slot(lane,j) = A[lane&15][8*(lane>>4)+j], B slot = B[8*(lane>>4)+j][lane&15]
//   C/D (verified, m89): row=(lane>>4)*4+reg, col=lane&15
// ---------------------------------------------------------------------------
__global__ __launch_bounds__(64) void qkv_mfma(
    const float* __restrict__ x, const short* __restrict__ wt,
    const float* __restrict__ bq, const float* __restrict__ bk,
    const float* __restrict__ bv,
    short* __restrict__ Qbf, short* __restrict__ Kbf, short* __restrict__ Vt)
{
    const int l = threadIdx.x;
    const int i = l & 15, g = l >> 4;
    const int rowbase = blockIdx.x * 16;
    const int sel = blockIdx.y;

    const short* ws   = wt + (size_t)sel * Dn * Cn;
    const float* bias = sel == 0 ? bq : (sel == 1 ? bk : bv);

    f32x4 acc[4];
    #pragma unroll
    for (int nt = 0; nt < 4; ++nt)
        #pragma unroll
        for (int r = 0; r < 4; ++r) acc[nt][r] = 0.f;

    const float* xrow = x + (size_t)(rowbase + i) * Cn;   // A row = lane&15

    for (int k0 = 0; k0 < Cn; k0 += 32) {
        float4 x0 = *reinterpret_cast<const float4*>(xrow + k0 + 8 * g);
        float4 x1 = *reinterpret_cast<const float4*>(xrow + k0 + 8 * g + 4);
        short8 af;
        af[0] = f2bf(x0.x); af[1] = f2bf(x0.y); af[2] = f2bf(x0.z); af[3] = f2bf(x0.w);
        af[4] = f2bf(x1.x); af[5] = f2bf(x1.y); af[6] = f2bf(x1.z); af[7] = f2bf(x1.w);
        #pragma unroll
        for (int nt = 0; nt < 4; ++nt) {
            short8 bf = *reinterpret_cast<const short8*>(
                ws + (size_t)(nt * 16 + i) * Cn + k0 + 8 * g);
            acc[nt] = __builtin_amdgcn_mfma_f32_16x16x32_bf16(af, bf, acc[nt], 0, 0, 0);
        }
    }

    #pragma unroll
    for (int r = 0; r < 4; ++r) {
        const int rho = rowbase + 4 * g + r;          // C/D row
        const int b = rho >> 11, t = rho & (Tn - 1);
        #pragma unroll
        for (int nt = 0; nt < 4; ++nt) {
            const int n = nt * 16 + i;                // C/D col
            const float val = acc[nt][r] + bias[n];
            if (sel == 0)      Qbf[(size_t)rho * Dn + n] = f2bf(val * 0.125f);
            else if (sel == 1) Kbf[(size_t)rho * Dn + n] = f2bf(val);
            else               Vt[((size_t)b * Dn + n) * Tn + t] = f2bf(val);
        }
    }
}

// ---------------------------------------------------------------------------
// Kernel 2: fused causal flash attention, KV-SPLIT ACROSS 4 WAVES.
// Grid (T/16, B), block = 4 waves.  All waves share the same 16 q-rows; wave
// w processes chunks kb ≡ w (mod 4) with an independent online softmax, then
// the 4 partials (m, l, unnormalized O) merge via LDS + one barrier:
//   M = max m_p ; L = Σ l_p e^{m_p-M} ; O = Σ O_p e^{m_p-M} ; out = O/L.
// Waves with zero chunks contribute m=-1e30 -> weight 0 (no special case).
// ---------------------------------------------------------------------------
__global__ __launch_bounds__(256) void attn_fused(
    const short* __restrict__ Qbf, const short* __restrict__ Kbf,
    const short* __restrict__ Vt, float* __restrict__ out)
{
    __shared__ __align__(16) short Plds[4][16][72];
    __shared__ float o_part[4][16][68];               // pad 68: bank-spread
    __shared__ float ml_part[4][2][16];               // [w][0]=m, [w][1]=l

    const int tid = threadIdx.x;
    const int w = tid >> 6, l = tid & 63;
    const int i = l & 15, g = l >> 4;
    const int b = blockIdx.y;
    const int qw = blockIdx.x * 16;                   // block's 16 q-rows

    const short* Qb = Qbf + (size_t)b * Tn * Dn;
    const short* Kb = Kbf + (size_t)b * Tn * Dn;
    const short* Vb = Vt + (size_t)b * Dn * Tn;

    // Q fragments (A row = lane&15), shared by all 4 waves
    short8 qf0 = *reinterpret_cast<const short8*>(Qb + (size_t)(qw + i) * Dn + 8 * g);
    short8 qf1 = *reinterpret_cast<const short8*>(Qb + (size_t)(qw + i) * Dn + 32 + 8 * g);

    f32x4 o4[4];
    f32x4 m, lsum;
    #pragma unroll
    for (int r = 0; r < 4; ++r) { m[r] = -1e30f; lsum[r] = 0.f; }
    #pragma unroll
    for (int dt = 0; dt < 4; ++dt)
        #pragma unroll
        for (int r = 0; r < 4; ++r) o4[dt][r] = 0.f;

    const int nch = (qw + 79) >> 6;                   // chunks covering keys <= qw+15
    for (int kb = w; kb < nch; kb += 4) {
        const int K0 = kb * 64;

        // ---- S = Q K^T ----
        f32x4 s[4];
        #pragma unroll
        for (int nt = 0; nt < 4; ++nt)
            #pragma unroll
            for (int r = 0; r < 4; ++r) s[nt][r] = 0.f;
        #pragma unroll
        for (int nt = 0; nt < 4; ++nt) {
            const short* kr = Kb + (size_t)(K0 + nt * 16 + i) * Dn + 8 * g;
            short8 kf0 = *reinterpret_cast<const short8*>(kr);
            short8 kf1 = *reinterpret_cast<const short8*>(kr + 32);
            s[nt] = __builtin_amdgcn_mfma_f32_16x16x32_bf16(qf0, kf0, s[nt], 0, 0, 0);
            s[nt] = __builtin_amdgcn_mfma_f32_16x16x32_bf16(qf1, kf1, s[nt], 0, 0, 0);
        }

        // ---- causal mask (only near the diagonal) ----
        if (K0 + 63 > qw) {
            #pragma unroll
            for (int nt = 0; nt < 4; ++nt)
                #pragma unroll
                for (int r = 0; r < 4; ++r) {
                    if (K0 + nt * 16 + i > qw + 4 * g + r) s[nt][r] = -1e30f;
                }
        }

        // ---- online softmax over this wave's chunk ----
        f32x4 rm;
        #pragma unroll
        for (int r = 0; r < 4; ++r)
            rm[r] = fmaxf(fmaxf(s[0][r], s[1][r]), fmaxf(s[2][r], s[3][r]));
        #pragma unroll
        for (int msk = 1; msk < 16; msk <<= 1)
            #pragma unroll
            for (int r = 0; r < 4; ++r) rm[r] = fmaxf(rm[r], __shfl_xor(rm[r], msk));

        f32x4 scl;
        #pragma unroll
        for (int r = 0; r < 4; ++r) {
            float mn = fmaxf(m[r], rm[r]);
            scl[r] = __expf(m[r] - mn);
            m[r] = mn;
            lsum[r] *= scl[r];
        }
        #pragma unroll
        for (int dt = 0; dt < 4; ++dt)
            #pragma unroll
            for (int r = 0; r < 4; ++r) o4[dt][r] *= scl[r];

        f32x4 rs;
        #pragma unroll
        for (int r = 0; r < 4; ++r) rs[r] = 0.f;
        #pragma unroll
        for (int nt = 0; nt < 4; ++nt)
            #pragma unroll
            for (int r = 0; r < 4; ++r) {
                float p = __expf(s[nt][r] - m[r]);
                rs[r] += p;
                Plds[w][4 * g + r][nt * 16 + i] = f2bf(p);
            }
        #pragma unroll
        for (int msk = 1; msk < 16; msk <<= 1)
            #pragma unroll
            for (int r = 0; r < 4; ++r) rs[r] += __shfl_xor(rs[r], msk);
        #pragma unroll
        for (int r = 0; r < 4; ++r) lsum[r] += rs[r];

        // wave-private LDS roundtrip: drain own writes, pin ordering
        asm volatile("s_waitcnt lgkmcnt(0)" ::: "memory");
        __builtin_amdgcn_sched_barrier(0);

        // ---- O += P V ----
        short8 pf0 = *reinterpret_cast<const short8*>(&Plds[w][i][8 * g]);
        short8 pf1 = *reinterpret_cast<const short8*>(&Plds[w][i][32 + 8 * g]);
        #pragma unroll
        for (int dt = 0; dt < 4; ++dt) {
            const short* vr = Vb + (size_t)(dt * 16 + i) * Tn + K0 + 8 * g;
            short8 vf0 = *reinterpret_cast<const short8*>(vr);
            short8 vf1 = *reinterpret_cast<const short8*>(vr + 32);
            o4[dt] = __builtin_amdgcn_mfma_f32_16x16x32_bf16(pf0, vf0, o4[dt], 0, 0, 0);
            o4[dt] = __builtin_amdgcn_mfma_f32_16x16x32_bf16(pf1, vf1, o4[dt], 0, 0, 0);
        }
    }

    // ---- publish partials ----
    #pragma unroll
    for (int dt = 0; dt < 4; ++dt)
        #pragma unroll
        for (int r = 0; r < 4; ++r)
            o_part[w][4 * g + r][dt * 16 + i] = o4[dt][r];
    if (i == 0) {
        #pragma unroll
        for (int r = 0; r < 4; ++r) {
            ml_part[w][0][4 * g + r] = m[r];
            ml_part[w][1][4 * g + r] = lsum[r];
        }
    }
    __syncthreads();

    // ---- merge: wave w owns output cols [16w, 16w+16), rows 4g+r ----
    #pragma unroll
    for (int r = 0; r < 4; ++r) {
        const int row = 4 * g + r;
        float m0 = ml_part[0][0][row], m1 = ml_part[1][0][row];
        float m2 = ml_part[2][0][row], m3 = ml_part[3][0][row];
        float M = fmaxf(fmaxf(m0, m1), fmaxf(m2, m3));
        float w0 = __expf(m0 - M), w1 = __expf(m1 - M);
        float w2 = __expf(m2 - M), w3 = __expf(m3 - M);
        float L = ml_part[0][1][row] * w0 + ml_part[1][1][row] * w1 +
                  ml_part[2][1][row] * w2 + ml_part[3][1][row] * w3;
        float O = o_part[0][row][w * 16 + i] * w0 + o_part[1][row][w * 16 + i] * w1 +
                  o_part[2][row][w * 16 + i] * w2 + o_part[3][row][w * 16 + i] * w3;
        out[((size_t)b * Tn + qw + row) * Dn + w * 16 + i] = O / L;
    }
}

// ---------------------------------------------------------------------------
extern "C" void kernel_launch(void* const* d_in, const int* in_sizes, int n_in,
                              void* d_out, int out_size, void* d_ws, size_t ws_size,
                              hipStream_t stream) {
    const float* x  = (const float*)d_in[0];
    const float* wq = (const float*)d_in[1];
    const float* wk = (const float*)d_in[2];
    const float* wv = (const float*)d_in[3];
    const float* bq = (const float*)d_in[4];
    const float* bk = (const float*)d_in[5];
    const float* bv = (const float*)d_in[6];
    float* out = (float*)d_out;

    short* wt  = (short*)d_ws;                       // 3*64*1024  bf16
    short* Qbf = wt + 3 * Dn * Cn;                   // 4*2048*64  bf16 each
    short* Kbf = Qbf + (size_t)Bn * Tn * Dn;
    short* Vt  = Kbf + (size_t)Bn * Tn * Dn;         // transposed (b,d,t)

    prep_w<<<48, 256, 0, stream>>>(wq, wk, wv, wt);
    qkv_mfma<<<dim3((Bn * Tn) / 16, 3), 64, 0, stream>>>(x, wt, bq, bk, bv, Qbf, Kbf, Vt);
    attn_fused<<<dim3(Tn / 16, Bn), 256, 0, stream>>>(Qbf, Kbf, Vt, out);
}